// Round 2
// baseline (235.544 us; speedup 1.0000x reference)
//
#include <hip/hip_runtime.h>
#include <hip/hip_bf16.h>

#define BATCH 8
#define SEQ 2048
#define HID 768
#define DIM 32
#define SCALE 0.17677669529663689f  // 1/sqrt(32)

typedef __attribute__((ext_vector_type(4))) float f32x4;
typedef __attribute__((ext_vector_type(8))) _Float16 f16x8;  // 8 f16 in 4 VGPRs

__device__ __forceinline__ short f2h(float f) {
  _Float16 h = (_Float16)f;  // v_cvt_f16_f32, RNE
  return __builtin_bit_cast(short, h);
}

// ---------------------------------------------------------------------------
// Kernel 0: effective weights (f16).
// Wt (f16, [96][768] = W_eff^T): cols 0-31 -> Wq^T@RF, 32-63 -> Wk^T@RF, 64-95 -> Wv.
// be (f32, [96]): bq@RF, bk@RF, bv.
// ---------------------------------------------------------------------------
__global__ __launch_bounds__(256) void prep_weights(
    const float* __restrict__ Wq, const float* __restrict__ bq,
    const float* __restrict__ Wk, const float* __restrict__ bk,
    const float* __restrict__ Wv, const float* __restrict__ bv,
    const float* __restrict__ RF, short* __restrict__ Wt, float* __restrict__ be) {
  int t = blockIdx.x * 256 + threadIdx.x;  // 0 .. 96*768-1
  int c = t / HID, h = t - c * HID;
  float acc;
  if (c < 64) {
    const float* W = (c < 32) ? Wq : Wk;
    int cc = c & 31;
    acc = 0.f;
    #pragma unroll
    for (int d = 0; d < 32; ++d) acc += W[d * HID + h] * RF[d * 32 + cc];
  } else {
    acc = Wv[(c - 64) * HID + h];
  }
  Wt[c * HID + h] = f2h(acc);
  if (h == 0) {
    float bacc;
    if (c < 64) {
      const float* bb = (c < 32) ? bq : bk;
      int cc = c & 31;
      bacc = 0.f;
      #pragma unroll
      for (int d = 0; d < 32; ++d) bacc += bb[d] * RF[d * 32 + cc];
    } else {
      bacc = bv[c - 64];
    }
    be[c] = bacc;
  }
}

// ---------------------------------------------------------------------------
// Kernel 1: fused QKV+RF projection. [16384,768]@[768,96] f16 MFMA.
// Outputs: qr (f16 [B*S][32], pre-scaled by 1/sqrt(D)), kr (f16 [B*S][32]),
//          vt (f16 [B][32][S], transposed).
// Block: 256 thr = 4 waves, 64 rows; wave w -> rows 16w..16w+15, all 96 cols.
// ---------------------------------------------------------------------------
__global__ __launch_bounds__(256) void qkv_kernel(
    const float* __restrict__ x, const short* __restrict__ Wt,
    const float* __restrict__ be, short* __restrict__ qr,
    short* __restrict__ kr, short* __restrict__ vt) {
  const int w = threadIdx.x >> 6;
  const int l = threadIdx.x & 63;
  const int g = l >> 4, c16 = l & 15;
  const int r0 = blockIdx.x * 64;
  const int arow = r0 + 16 * w + c16;            // A-frag row (row = lane&15)
  const float* xp = x + (size_t)arow * HID + 8 * g;

  f32x4 acc[6];
  #pragma unroll
  for (int i = 0; i < 6; ++i) acc[i] = f32x4{0.f, 0.f, 0.f, 0.f};

  for (int kc = 0; kc < 24; ++kc) {
    f32x4 x0 = *(const f32x4*)(xp + kc * 32);
    f32x4 x1 = *(const f32x4*)(xp + kc * 32 + 4);
    f16x8 a;
    a[0] = (_Float16)x0[0]; a[1] = (_Float16)x0[1];
    a[2] = (_Float16)x0[2]; a[3] = (_Float16)x0[3];
    a[4] = (_Float16)x1[0]; a[5] = (_Float16)x1[1];
    a[6] = (_Float16)x1[2]; a[7] = (_Float16)x1[3];
    const short* wp = Wt + c16 * HID + kc * 32 + 8 * g;
    #pragma unroll
    for (int ct = 0; ct < 6; ++ct) {
      f16x8 bfr = *(const f16x8*)(wp + ct * 16 * HID);
      acc[ct] = __builtin_amdgcn_mfma_f32_16x16x32_f16(a, bfr, acc[ct], 0, 0, 0);
    }
  }

  // C layout: col = lane&15, row = 4*(lane>>4)+reg  [verified m89; dtype-independent]
  const int srow_base = r0 + 16 * w + 4 * g;
  #pragma unroll
  for (int ct = 0; ct < 6; ++ct) {
    int c = 16 * ct + c16;
    float bias = be[c];
    #pragma unroll
    for (int r = 0; r < 4; ++r) {
      int s = srow_base + r;
      float v = acc[ct][r] + bias;
      if (ct < 2) {
        qr[(size_t)s * DIM + c] = f2h(v * SCALE);
      } else if (ct < 4) {
        kr[(size_t)s * DIM + (c - 32)] = f2h(v);
      } else {
        int b = s >> 11;
        vt[((size_t)b * DIM + (c - 64)) * SEQ + (s & 2047)] = f2h(v);
      }
    }
  }
}

// ---------------------------------------------------------------------------
// Kernel 2: fused scores + softmax + probs write + PV.
// Grid (64,8): block = (qtile of 32 rows, batch). 4 waves:
//   w&1 = row-half (16 rows each), w>>1 = kt parity (each wave does 16 of 32
//   kt-steps of 64 cols). Two passes: (1) online m,l; merge via LDS;
//   (2) recompute scores, write probs (nontemporal), PV MFMA via LDS bounce.
// ---------------------------------------------------------------------------
__global__ __launch_bounds__(256) void attn_kernel(
    const short* __restrict__ qr, const short* __restrict__ kr,
    const short* __restrict__ vt, float* __restrict__ out,
    float* __restrict__ probs) {
  const int qtile = blockIdx.x;   // 0..63
  const int b = blockIdx.y;       // 0..7
  const int w = threadIdx.x >> 6;
  const int l = threadIdx.x & 63;
  const int g = l >> 4, c16 = l & 15;
  const int rowhalf = w & 1, par = w >> 1;
  const int qbase = qtile * 32 + 16 * rowhalf;

  __shared__ __align__(16) short p_lds[4][1024];  // per-wave 16x64 f16, XOR-swizzled
  __shared__ float m_lds[4][16], l_lds[4][16];
  __shared__ float o_lds[2][16][32];

  const short* krb = kr + (size_t)b * SEQ * DIM + 8 * g;
  const short* vtb = vt + (size_t)b * DIM * SEQ + 8 * g;
  f16x8 aq = *(const f16x8*)(qr + (size_t)(b * SEQ + qbase + c16) * DIM + 8 * g);

  float m[4] = {-1e30f, -1e30f, -1e30f, -1e30f};
  float lp[4] = {0.f, 0.f, 0.f, 0.f};

  // ---- pass 1: online row max + exp-sum (this wave's kt parity subset) ----
  for (int it = 0; it < 16; ++it) {
    int kbase = (2 * it + par) * 64;
    f32x4 sc[4];
    #pragma unroll
    for (int t = 0; t < 4; ++t) {
      f16x8 bk = *(const f16x8*)(krb + (size_t)(kbase + 16 * t + c16) * DIM);
      f32x4 z = f32x4{0.f, 0.f, 0.f, 0.f};
      sc[t] = __builtin_amdgcn_mfma_f32_16x16x32_f16(aq, bk, z, 0, 0, 0);
    }
    #pragma unroll
    for (int r = 0; r < 4; ++r) {
      float mx = fmaxf(fmaxf(sc[0][r], sc[1][r]), fmaxf(sc[2][r], sc[3][r]));
      mx = fmaxf(mx, __shfl_xor(mx, 1));
      mx = fmaxf(mx, __shfl_xor(mx, 2));
      mx = fmaxf(mx, __shfl_xor(mx, 4));
      mx = fmaxf(mx, __shfl_xor(mx, 8));
      float mn = fmaxf(m[r], mx);
      float corr = __expf(m[r] - mn);
      float sum = __expf(sc[0][r] - mn) + __expf(sc[1][r] - mn) +
                  __expf(sc[2][r] - mn) + __expf(sc[3][r] - mn);
      lp[r] = lp[r] * corr + sum;
      m[r] = mn;
    }
  }
  // butterfly-sum l across the 16-lane row group
  #pragma unroll
  for (int r = 0; r < 4; ++r) {
    lp[r] += __shfl_xor(lp[r], 1);
    lp[r] += __shfl_xor(lp[r], 2);
    lp[r] += __shfl_xor(lp[r], 4);
    lp[r] += __shfl_xor(lp[r], 8);
  }
  // merge (m,l) across kt-parity partner waves (w ^ 2)
  if (c16 == 0) {
    #pragma unroll
    for (int r = 0; r < 4; ++r) {
      m_lds[w][4 * g + r] = m[r];
      l_lds[w][4 * g + r] = lp[r];
    }
  }
  __syncthreads();
  float mf[4], inv_l[4];
  {
    int pw = w ^ 2;
    #pragma unroll
    for (int r = 0; r < 4; ++r) {
      float mb = m_lds[pw][4 * g + r], lb = l_lds[pw][4 * g + r];
      float mm = fmaxf(m[r], mb);
      float lf = lp[r] * __expf(m[r] - mm) + lb * __expf(mb - mm);
      mf[r] = mm;
      inv_l[r] = 1.0f / lf;
    }
  }

  // ---- pass 2: recompute scores, write probs, PV ----
  f32x4 oacc[2] = {f32x4{0.f, 0.f, 0.f, 0.f}, f32x4{0.f, 0.f, 0.f, 0.f}};
  char* pwb = (char*)(&p_lds[w][0]);
  float* prow_base = probs + ((size_t)b * SEQ + qbase + 4 * g) * SEQ + c16;

  for (int it = 0; it < 16; ++it) {
    int kbase = (2 * it + par) * 64;
    f32x4 sc[4];
    #pragma unroll
    for (int t = 0; t < 4; ++t) {
      f16x8 bk = *(const f16x8*)(krb + (size_t)(kbase + 16 * t + c16) * DIM);
      f32x4 z = f32x4{0.f, 0.f, 0.f, 0.f};
      sc[t] = __builtin_amdgcn_mfma_f32_16x16x32_f16(aq, bk, z, 0, 0, 0);
    }
    #pragma unroll
    for (int t = 0; t < 4; ++t) {
      #pragma unroll
      for (int r = 0; r < 4; ++r) {
        float p = __expf(sc[t][r] - mf[r]) * inv_l[r];
        __builtin_nontemporal_store(p, prow_base + (size_t)r * SEQ + kbase + 16 * t);
        int roww = 4 * g + r, colw = 16 * t + c16;
        int byteoff = roww * 128 + ((colw * 2) ^ ((roww & 7) << 4));
        *(short*)(pwb + byteoff) = f2h(p);
      }
    }
    __asm__ __volatile__("" ::: "memory");  // order LDS writes before reads (same wave)
    #pragma unroll
    for (int kc = 0; kc < 2; ++kc) {
      int rbyte = c16 * 128 + ((64 * kc + 16 * g) ^ ((c16 & 7) << 4));
      f16x8 ap = *(const f16x8*)(pwb + rbyte);
      #pragma unroll
      for (int ct = 0; ct < 2; ++ct) {
        f16x8 bv = *(const f16x8*)(vtb + (size_t)(16 * ct + c16) * SEQ + kbase + 32 * kc);
        oacc[ct] = __builtin_amdgcn_mfma_f32_16x16x32_f16(ap, bv, oacc[ct], 0, 0, 0);
      }
    }
    __asm__ __volatile__("" ::: "memory");  // keep next-iter LDS writes after reads
  }

  // merge out partials across kt-parity waves, store
  if (par == 1) {
    #pragma unroll
    for (int ct = 0; ct < 2; ++ct)
      #pragma unroll
      for (int r = 0; r < 4; ++r)
        o_lds[rowhalf][4 * g + r][16 * ct + c16] = oacc[ct][r];
  }
  __syncthreads();
  if (par == 0) {
    #pragma unroll
    for (int ct = 0; ct < 2; ++ct)
      #pragma unroll
      for (int r = 0; r < 4; ++r) {
        float v = oacc[ct][r] + o_lds[rowhalf][4 * g + r][16 * ct + c16];
        out[((size_t)b * SEQ + qbase + 4 * g + r) * DIM + 16 * ct + c16] = v;
      }
  }
}

// ---------------------------------------------------------------------------
// Workspace layout (bytes):
//   Wt:  0        .. 147456   (96*768 f16)
//   be:  147456   .. 147840   (96 f32)
//   qr:  147840   .. +1 MiB   (8*2048*32 f16, pre-scaled)
//   kr:  +1 MiB   .. +2 MiB
//   vt:  +2 MiB   .. +3 MiB   ([B][32][S] f16)
// Total ~3.15 MB.
// ---------------------------------------------------------------------------
extern "C" void kernel_launch(void* const* d_in, const int* in_sizes, int n_in,
                              void* d_out, int out_size, void* d_ws, size_t ws_size,
                              hipStream_t stream) {
  const float* x  = (const float*)d_in[0];
  const float* Wq = (const float*)d_in[1];
  const float* bq = (const float*)d_in[2];
  const float* Wk = (const float*)d_in[3];
  const float* bk = (const float*)d_in[4];
  const float* Wv = (const float*)d_in[5];
  const float* bv = (const float*)d_in[6];
  const float* RF = (const float*)d_in[7];

  char* ws = (char*)d_ws;
  short* Wt  = (short*)ws;
  float* be  = (float*)(ws + 147456);
  short* qrp = (short*)(ws + 147840);
  short* krp = (short*)(ws + 147840 + 1048576);
  short* vtp = (short*)(ws + 147840 + 2097152);

  float* out = (float*)d_out;
  float* probs = out + (size_t)BATCH * SEQ * DIM;

  hipLaunchKernelGGL(prep_weights, dim3(288), dim3(256), 0, stream,
                     Wq, bq, Wk, bk, Wv, bv, RF, Wt, be);
  hipLaunchKernelGGL(qkv_kernel, dim3(256), dim3(256), 0, stream,
                     x, Wt, be, qrp, krp, vtp);
  hipLaunchKernelGGL(attn_kernel, dim3(64, 8), dim3(256), 0, stream,
                     qrp, krp, vtp, out, probs);
}

// Round 4
// 232.053 us; speedup vs baseline: 1.0150x; 1.0150x over previous
//
#include <hip/hip_runtime.h>
#include <hip/hip_bf16.h>

#define BATCH 8
#define SEQ 2048
#define HID 768
#define DIM 32
// (1/sqrt(32)) * log2(e): scores land in log2 domain
#define SCALE2 (0.17677669529663689f * 1.4426950408889634f)
#define M2 11.541560327111707f  // 8 * log2(e)

typedef __attribute__((ext_vector_type(4))) float f32x4;
typedef __attribute__((ext_vector_type(8))) _Float16 f16x8;  // 8 f16 in 4 VGPRs
typedef __attribute__((ext_vector_type(2))) _Float16 f16x2;
typedef __attribute__((ext_vector_type(2))) unsigned int u32x2;

__device__ __forceinline__ short f2h(float f) {
  _Float16 h = (_Float16)f;  // v_cvt_f16_f32, RNE
  return __builtin_bit_cast(short, h);
}

// ---------------------------------------------------------------------------
// Kernel 0: effective weights (f16).
// Wt (f16, [96][768] = W_eff^T): cols 0-31 -> Wq^T@RF, 32-63 -> Wk^T@RF, 64-95 -> Wv.
// be (f32, [96]): bq@RF, bk@RF, bv.
// ---------------------------------------------------------------------------
__global__ __launch_bounds__(256) void prep_weights(
    const float* __restrict__ Wq, const float* __restrict__ bq,
    const float* __restrict__ Wk, const float* __restrict__ bk,
    const float* __restrict__ Wv, const float* __restrict__ bv,
    const float* __restrict__ RF, short* __restrict__ Wt, float* __restrict__ be) {
  int t = blockIdx.x * 256 + threadIdx.x;  // 0 .. 96*768-1
  int c = t / HID, h = t - c * HID;
  float acc;
  if (c < 64) {
    const float* W = (c < 32) ? Wq : Wk;
    int cc = c & 31;
    acc = 0.f;
    #pragma unroll
    for (int d = 0; d < 32; ++d) acc += W[d * HID + h] * RF[d * 32 + cc];
  } else {
    acc = Wv[(c - 64) * HID + h];
  }
  Wt[c * HID + h] = f2h(acc);
  if (h == 0) {
    float bacc;
    if (c < 64) {
      const float* bb = (c < 32) ? bq : bk;
      int cc = c & 31;
      bacc = 0.f;
      #pragma unroll
      for (int d = 0; d < 32; ++d) bacc += bb[d] * RF[d * 32 + cc];
    } else {
      bacc = bv[c - 64];
    }
    be[c] = bacc;
  }
}

// ---------------------------------------------------------------------------
// Kernel 1: fused QKV+RF projection. [16384,768]@[768,96] f16 MFMA.
// qr is pre-scaled by SCALE2 (scores come out in log2 domain).
// ---------------------------------------------------------------------------
__global__ __launch_bounds__(256) void qkv_kernel(
    const float* __restrict__ x, const short* __restrict__ Wt,
    const float* __restrict__ be, short* __restrict__ qr,
    short* __restrict__ kr, short* __restrict__ vt) {
  const int w = threadIdx.x >> 6;
  const int l = threadIdx.x & 63;
  const int g = l >> 4, c16 = l & 15;
  const int r0 = blockIdx.x * 64;
  const int arow = r0 + 16 * w + c16;            // A-frag row (row = lane&15)
  const float* xp = x + (size_t)arow * HID + 8 * g;

  f32x4 acc[6];
  #pragma unroll
  for (int i = 0; i < 6; ++i) acc[i] = f32x4{0.f, 0.f, 0.f, 0.f};

  #pragma unroll 4
  for (int kc = 0; kc < 24; ++kc) {
    f32x4 x0 = *(const f32x4*)(xp + kc * 32);
    f32x4 x1 = *(const f32x4*)(xp + kc * 32 + 4);
    f16x8 a;
    a[0] = (_Float16)x0[0]; a[1] = (_Float16)x0[1];
    a[2] = (_Float16)x0[2]; a[3] = (_Float16)x0[3];
    a[4] = (_Float16)x1[0]; a[5] = (_Float16)x1[1];
    a[6] = (_Float16)x1[2]; a[7] = (_Float16)x1[3];
    const short* wp = Wt + c16 * HID + kc * 32 + 8 * g;
    #pragma unroll
    for (int ct = 0; ct < 6; ++ct) {
      f16x8 bfr = *(const f16x8*)(wp + ct * 16 * HID);
      acc[ct] = __builtin_amdgcn_mfma_f32_16x16x32_f16(a, bfr, acc[ct], 0, 0, 0);
    }
  }

  // C layout: col = lane&15, row = 4*(lane>>4)+reg  [m89; dtype-independent]
  const int srow_base = r0 + 16 * w + 4 * g;
  #pragma unroll
  for (int ct = 0; ct < 6; ++ct) {
    int c = 16 * ct + c16;
    float bias = be[c];
    #pragma unroll
    for (int r = 0; r < 4; ++r) {
      int s = srow_base + r;
      float v = acc[ct][r] + bias;
      if (ct < 2) {
        qr[(size_t)s * DIM + c] = f2h(v * SCALE2);
      } else if (ct < 4) {
        kr[(size_t)s * DIM + (c - 32)] = f2h(v);
      } else {
        int b = s >> 11;
        vt[((size_t)b * DIM + (c - 64)) * SEQ + (s & 2047)] = f2h(v);
      }
    }
  }
}

// ---------------------------------------------------------------------------
// Kernel 2: fused scores + softmax + probs write + PV.
// Flat grid 512: b = bid&7 (XCD affinity: one batch per XCD's L2), qtile = bid>>3.
// 4 waves: w&1 = row-half (16 rows), w>>1 = kt parity (16 of 32 kt-steps).
// Fixed-max softmax in log2 domain: p = exp2(s2 + c2[row]), c2 = -(M2 + log2 l).
// Score-tile column map: tile t, frag-col c16 <-> global col kbase + 4*c16 + t,
// so each lane owns 4 consecutive probs columns -> float4 stores + b64 LDS writes.
// ---------------------------------------------------------------------------
__global__ __launch_bounds__(256) void attn_kernel(
    const short* __restrict__ qr, const short* __restrict__ kr,
    const short* __restrict__ vt, float* __restrict__ out,
    float* __restrict__ probs) {
  const int bid = blockIdx.x;
  const int b = bid & 7;          // XCD-affine batch
  const int qtile = bid >> 3;     // 0..63
  const int w = threadIdx.x >> 6;
  const int l = threadIdx.x & 63;
  const int g = l >> 4, c16 = l & 15;
  const int rowhalf = w & 1, par = w >> 1;
  const int qbase = qtile * 32 + 16 * rowhalf;

  __shared__ __align__(16) short p_lds[4][1024];  // per-wave 16x64 f16, XOR-swizzled
  __shared__ float l_lds[4][16];
  __shared__ float o_lds[2][16][32];

  const short* krb = kr + (size_t)b * SEQ * DIM + 8 * g;
  const short* vtb = vt + (size_t)b * DIM * SEQ + 8 * g;
  f16x8 aq = *(const f16x8*)(qr + (size_t)(b * SEQ + qbase + c16) * DIM + 8 * g);

  float lp[4] = {0.f, 0.f, 0.f, 0.f};

  // ---- pass 1: denominator accumulation (fixed max M2, log2 domain) ----
  for (int it = 0; it < 16; ++it) {
    int kbase = (2 * it + par) * 64;
    #pragma unroll
    for (int t = 0; t < 4; ++t) {
      f16x8 bk = *(const f16x8*)(krb + (size_t)(kbase + 4 * c16 + t) * DIM);
      f32x4 z = f32x4{0.f, 0.f, 0.f, 0.f};
      f32x4 sc = __builtin_amdgcn_mfma_f32_16x16x32_f16(aq, bk, z, 0, 0, 0);
      #pragma unroll
      for (int r = 0; r < 4; ++r) lp[r] += exp2f(sc[r] - M2);
    }
  }
  // butterfly-sum l across the 16-lane row group (c16 dimension)
  #pragma unroll
  for (int r = 0; r < 4; ++r) {
    lp[r] += __shfl_xor(lp[r], 1);
    lp[r] += __shfl_xor(lp[r], 2);
    lp[r] += __shfl_xor(lp[r], 4);
    lp[r] += __shfl_xor(lp[r], 8);
  }
  // merge l across kt-parity partner waves (w ^ 2); c2[r] = -(M2 + log2 l)
  if (c16 == 0) {
    #pragma unroll
    for (int r = 0; r < 4; ++r) l_lds[w][4 * g + r] = lp[r];
  }
  __syncthreads();
  float c2[4];
  {
    int pw = w ^ 2;
    #pragma unroll
    for (int r = 0; r < 4; ++r) {
      float lf = lp[r] + l_lds[pw][4 * g + r];
      c2[r] = -(M2 + __log2f(lf));
    }
  }

  // ---- pass 2: recompute scores, write probs (float4 NT), PV via LDS ----
  f32x4 oacc[2] = {f32x4{0.f, 0.f, 0.f, 0.f}, f32x4{0.f, 0.f, 0.f, 0.f}};
  char* pwb = (char*)(&p_lds[w][0]);
  float* prow = probs + ((size_t)b * SEQ + qbase + 4 * g) * SEQ + 4 * c16;

  for (int it = 0; it < 16; ++it) {
    int kbase = (2 * it + par) * 64;
    f32x4 sc[4];
    #pragma unroll
    for (int t = 0; t < 4; ++t) {
      f16x8 bk = *(const f16x8*)(krb + (size_t)(kbase + 4 * c16 + t) * DIM);
      f32x4 z = f32x4{0.f, 0.f, 0.f, 0.f};
      sc[t] = __builtin_amdgcn_mfma_f32_16x16x32_f16(aq, bk, z, 0, 0, 0);
    }
    #pragma unroll
    for (int r = 0; r < 4; ++r) {
      f32x4 pv;
      pv[0] = exp2f(sc[0][r] + c2[r]);
      pv[1] = exp2f(sc[1][r] + c2[r]);
      pv[2] = exp2f(sc[2][r] + c2[r]);
      pv[3] = exp2f(sc[3][r] + c2[r]);
      __builtin_nontemporal_store(pv, (f32x4*)(prow + (size_t)r * SEQ + kbase));
      u32x2 ph;
      ph[0] = __builtin_bit_cast(unsigned int, __builtin_amdgcn_cvt_pkrtz(pv[0], pv[1]));
      ph[1] = __builtin_bit_cast(unsigned int, __builtin_amdgcn_cvt_pkrtz(pv[2], pv[3]));
      int roww = 4 * g + r;
      int byteoff = roww * 128 + ((8 * c16) ^ ((roww & 7) << 4));
      *(u32x2*)(pwb + byteoff) = ph;  // 8B-aligned, 2-way max bank alias
    }
    __asm__ __volatile__("" ::: "memory");  // order LDS writes before reads (same wave)
    #pragma unroll
    for (int kc = 0; kc < 2; ++kc) {
      int rbyte = c16 * 128 + ((64 * kc + 16 * g) ^ ((c16 & 7) << 4));
      f16x8 ap = *(const f16x8*)(pwb + rbyte);
      #pragma unroll
      for (int ct = 0; ct < 2; ++ct) {
        f16x8 bv = *(const f16x8*)(vtb + (size_t)(16 * ct + c16) * SEQ + kbase + 32 * kc);
        oacc[ct] = __builtin_amdgcn_mfma_f32_16x16x32_f16(ap, bv, oacc[ct], 0, 0, 0);
      }
    }
    __asm__ __volatile__("" ::: "memory");  // keep next-iter LDS writes after reads
  }

  // merge out partials across kt-parity waves, store
  if (par == 1) {
    #pragma unroll
    for (int ct = 0; ct < 2; ++ct)
      #pragma unroll
      for (int r = 0; r < 4; ++r)
        o_lds[rowhalf][4 * g + r][16 * ct + c16] = oacc[ct][r];
  }
  __syncthreads();
  if (par == 0) {
    #pragma unroll
    for (int ct = 0; ct < 2; ++ct)
      #pragma unroll
      for (int r = 0; r < 4; ++r) {
        float v = oacc[ct][r] + o_lds[rowhalf][4 * g + r][16 * ct + c16];
        out[((size_t)b * SEQ + qbase + 4 * g + r) * DIM + 16 * ct + c16] = v;
      }
  }
}

// ---------------------------------------------------------------------------
// Workspace layout (bytes):
//   Wt:  0        .. 147456   (96*768 f16)
//   be:  147456   .. 147840   (96 f32)
//   qr:  147840   .. +1 MiB   (f16, pre-scaled by SCALE2)
//   kr:  +1 MiB   .. +2 MiB
//   vt:  +2 MiB   .. +3 MiB   ([B][32][S] f16)
// ---------------------------------------------------------------------------
extern "C" void kernel_launch(void* const* d_in, const int* in_sizes, int n_in,
                              void* d_out, int out_size, void* d_ws, size_t ws_size,
                              hipStream_t stream) {
  const float* x  = (const float*)d_in[0];
  const float* Wq = (const float*)d_in[1];
  const float* bq = (const float*)d_in[2];
  const float* Wk = (const float*)d_in[3];
  const float* bk = (const float*)d_in[4];
  const float* Wv = (const float*)d_in[5];
  const float* bv = (const float*)d_in[6];
  const float* RF = (const float*)d_in[7];

  char* ws = (char*)d_ws;
  short* Wt  = (short*)ws;
  float* be  = (float*)(ws + 147456);
  short* qrp = (short*)(ws + 147840);
  short* krp = (short*)(ws + 147840 + 1048576);
  short* vtp = (short*)(ws + 147840 + 2097152);

  float* out = (float*)d_out;
  float* probs = out + (size_t)BATCH * SEQ * DIM;

  hipLaunchKernelGGL(prep_weights, dim3(288), dim3(256), 0, stream,
                     Wq, bq, Wk, bk, Wv, bv, RF, Wt, be);
  hipLaunchKernelGGL(qkv_kernel, dim3(256), dim3(256), 0, stream,
                     x, Wt, be, qrp, krp, vtp);
  hipLaunchKernelGGL(attn_kernel, dim3(512), dim3(256), 0, stream,
                     qrp, krp, vtp, out, probs);
}